// Round 1
// baseline (11486.360 us; speedup 1.0000x reference)
//
#include <hip/hip_runtime.h>

#define TT 512
#define HROWS 204   // 4*51 gate rows
#define RPAD 208
#define KPAD 52     // hidden padded to 52 = 4*13

__device__ __forceinline__ float fsig(float x) {
    float e = __expf(-x);
    return __fdividef(1.f, 1.f + e);
}
__device__ __forceinline__ float ftanh_(float x) {
    float t = __expf(-2.f * fabsf(x));
    float r = __fdividef(1.f - t, 1.f + t);
    return copysignf(r, x);
}

__global__ __launch_bounds__(256, 2) void lstm_seq_kernel(
    const float* __restrict__ X,
    const float* __restrict__ Wih1, const float* __restrict__ Whh1,
    const float* __restrict__ bih1, const float* __restrict__ bhh1,
    const float* __restrict__ Wih2, const float* __restrict__ Whh2,
    const float* __restrict__ bih2, const float* __restrict__ bhh2,
    float* __restrict__ out)
{
    __shared__ float W1[RPAD * KPAD];   // 43264 B, row stride 52 floats (16B-aligned rows)
    __shared__ float bs1[RPAD];         // bih1+bhh1
    __shared__ float wi1[RPAD];         // Wih1 column
    __shared__ float hbuf[KPAD * 64];   // [k][lane] h1 exchange, 13312 B
    __shared__ float pbuf[4 * 64 * 4];  // [wave][lane][gate] float4 layer-2 partials, 4096 B

    const int tid  = threadIdx.x;
    const int w    = tid >> 6;
    const int lane = tid & 63;
    const int b    = blockIdx.x * 64 + lane;
    const int qs   = w * 13;

    // ---- stage weights into LDS ----
    for (int i = tid; i < RPAD * KPAD; i += 256) {
        int r = i / KPAD, k = i - r * KPAD;
        W1[i] = (r < HROWS && k < 51) ? Whh1[r * 51 + k] : 0.f;
    }
    for (int r = tid; r < RPAD; r += 256) {
        bs1[r] = (r < HROWS) ? (bih1[r] + bhh1[r]) : 0.f;
        wi1[r] = (r < HROWS) ? Wih1[r] : 0.f;
    }

    // per-wave layer-2 weight slice in registers (static indexing only)
    float w2r[4][13];
    #pragma unroll
    for (int g = 0; g < 4; ++g) {
        #pragma unroll
        for (int jl = 0; jl < 13; ++jl) {
            int l = qs + jl;
            w2r[g][jl] = (l < 51) ? Wih2[g * 51 + l] : 0.f;
        }
    }
    float whh2r[4], bs2r[4];
    #pragma unroll
    for (int g = 0; g < 4; ++g) { whh2r[g] = Whh2[g]; bs2r[g] = bih2[g] + bhh2[g]; }

    float h1[KPAD];
    float c1[13];
    #pragma unroll
    for (int k = 0; k < KPAD; ++k) h1[k] = 0.f;
    #pragma unroll
    for (int j = 0; j < 13; ++j) c1[j] = 0.f;
    float h2 = 0.f, c2 = 0.f;

    __syncthreads();

    float xr = X[b * TT];

    for (int t = 0; t < TT; ++t) {
        float xnext = X[b * TT + (t < TT - 1 ? t + 1 : TT - 1)];

        // ---- layer-1 gates + state update for this wave's hidden slice ----
        #pragma unroll
        for (int jl = 0; jl < 13; ++jl) {
            int l = qs + jl;
            float acc[4];
            #pragma unroll
            for (int g = 0; g < 4; ++g) {
                int row = g * 51 + l;
                float a = bs1[row] + wi1[row] * xr;
                const float4* wr = (const float4*)&W1[row * KPAD];
                #pragma unroll
                for (int kq = 0; kq < 13; ++kq) {
                    float4 wv = wr[kq];
                    a += wv.x * h1[4*kq]   + wv.y * h1[4*kq+1]
                       + wv.z * h1[4*kq+2] + wv.w * h1[4*kq+3];
                }
                acc[g] = a;
            }
            float ig = fsig(acc[0]);
            float fg = fsig(acc[1]);
            float gg = ftanh_(acc[2]);
            float og = fsig(acc[3]);
            float c  = fg * c1[jl] + ig * gg;
            c1[jl] = c;
            hbuf[l * 64 + lane] = og * ftanh_(c);  // safe: prior readers done at last barrier
        }

        // ---- layer-2 partial gate sums over this wave's (new) c1 slice ----
        float p0 = 0.f, p1 = 0.f, p2 = 0.f, p3 = 0.f;
        #pragma unroll
        for (int jl = 0; jl < 13; ++jl) {
            p0 += w2r[0][jl] * c1[jl];
            p1 += w2r[1][jl] * c1[jl];
            p2 += w2r[2][jl] * c1[jl];
            p3 += w2r[3][jl] * c1[jl];
        }
        ((float4*)pbuf)[w * 64 + lane] = make_float4(p0, p1, p2, p3);

        __syncthreads();

        // reload full h1 (next step) and finish layer-2 (this step)
        #pragma unroll
        for (int k = 0; k < 51; ++k) h1[k] = hbuf[k * 64 + lane];
        h1[51] = 0.f;

        float s0 = bs2r[0] + whh2r[0] * h2;
        float s1 = bs2r[1] + whh2r[1] * h2;
        float s2 = bs2r[2] + whh2r[2] * h2;
        float s3 = bs2r[3] + whh2r[3] * h2;
        #pragma unroll
        for (int ww = 0; ww < 4; ++ww) {
            float4 p = ((const float4*)pbuf)[ww * 64 + lane];
            s0 += p.x; s1 += p.y; s2 += p.z; s3 += p.w;
        }
        float i2 = fsig(s0), f2 = fsig(s1), g2 = ftanh_(s2), o2 = fsig(s3);
        c2 = f2 * c2 + i2 * g2;
        h2 = o2 * ftanh_(c2);

        __syncthreads();
        xr = xnext;
    }

    // ---- extra step after the scan: lstm1(input=c2), then lstm2(input=c1_new) -> output = c2_new ----
    {
        float xe = c2;
        #pragma unroll
        for (int jl = 0; jl < 13; ++jl) {
            int l = qs + jl;
            float acc[4];
            #pragma unroll
            for (int g = 0; g < 4; ++g) {
                int row = g * 51 + l;
                float a = bs1[row] + wi1[row] * xe;
                const float4* wr = (const float4*)&W1[row * KPAD];
                #pragma unroll
                for (int kq = 0; kq < 13; ++kq) {
                    float4 wv = wr[kq];
                    a += wv.x * h1[4*kq]   + wv.y * h1[4*kq+1]
                       + wv.z * h1[4*kq+2] + wv.w * h1[4*kq+3];
                }
                acc[g] = a;
            }
            float ig = fsig(acc[0]);
            float fg = fsig(acc[1]);
            float gg = ftanh_(acc[2]);
            c1[jl] = fg * c1[jl] + ig * gg;
        }
        float p0 = 0.f, p1 = 0.f, p2 = 0.f, p3 = 0.f;
        #pragma unroll
        for (int jl = 0; jl < 13; ++jl) {
            p0 += w2r[0][jl] * c1[jl];
            p1 += w2r[1][jl] * c1[jl];
            p2 += w2r[2][jl] * c1[jl];
            p3 += w2r[3][jl] * c1[jl];
        }
        ((float4*)pbuf)[w * 64 + lane] = make_float4(p0, p1, p2, p3);
        __syncthreads();

        float s0 = bs2r[0] + whh2r[0] * h2;
        float s1 = bs2r[1] + whh2r[1] * h2;
        float s2 = bs2r[2] + whh2r[2] * h2;
        #pragma unroll
        for (int ww = 0; ww < 4; ++ww) {
            float4 p = ((const float4*)pbuf)[ww * 64 + lane];
            s0 += p.x; s1 += p.y; s2 += p.z;
        }
        float i2 = fsig(s0), f2 = fsig(s1), g2 = ftanh_(s2);
        float outv = f2 * c2 + i2 * g2;   // output = new cell state of lstm2
        if (w == 0) out[b] = outv;
    }
}

extern "C" void kernel_launch(void* const* d_in, const int* in_sizes, int n_in,
                              void* d_out, int out_size, void* d_ws, size_t ws_size,
                              hipStream_t stream) {
    const float* X    = (const float*)d_in[0];
    const float* Wih1 = (const float*)d_in[1];
    const float* Whh1 = (const float*)d_in[2];
    const float* bih1 = (const float*)d_in[3];
    const float* bhh1 = (const float*)d_in[4];
    const float* Wih2 = (const float*)d_in[5];
    const float* Whh2 = (const float*)d_in[6];
    const float* bih2 = (const float*)d_in[7];
    const float* bhh2 = (const float*)d_in[8];
    float* out = (float*)d_out;

    lstm_seq_kernel<<<128, 256, 0, stream>>>(X, Wih1, Whh1, bih1, bhh1,
                                             Wih2, Whh2, bih2, bhh2, out);
}

// Round 2
// 5368.923 us; speedup vs baseline: 2.1394x; 2.1394x over previous
//
#include <hip/hip_runtime.h>

#define TT 512
#define NB 32        // batch per block
#define NSL 26       // hidden slices per block
#define KH 52        // padded hidden (51 -> 52)
#define HROWS 204    // 4*51 gate rows
#define RPAD 208
#define NTHREADS 832 // 13 waves

__device__ __forceinline__ float fsig(float x) {
    float e = __expf(-x);
    return __fdividef(1.f, 1.f + e);
}
__device__ __forceinline__ float ftanh_(float x) {
    float t = __expf(-2.f * fabsf(x));
    float r = __fdividef(1.f - t, 1.f + t);
    return copysignf(r, x);
}

__global__ __launch_bounds__(NTHREADS, 1) void lstm_seq_kernel(
    const float* __restrict__ X,
    const float* __restrict__ Wih1, const float* __restrict__ Whh1,
    const float* __restrict__ bih1, const float* __restrict__ bhh1,
    const float* __restrict__ Wih2, const float* __restrict__ Whh2,
    const float* __restrict__ bih2, const float* __restrict__ bhh2,
    float* __restrict__ out)
{
    __shared__ float W1[RPAD * KH];      // 43264 B, row stride 52 floats (208B, 16B-aligned)
    __shared__ float bs1[RPAD];          // 832 B
    __shared__ float wi1[RPAD];          // 832 B
    __shared__ float hbuf[KH * NB];      // 6656 B  [k][b32]
    __shared__ float pbuf[NSL * NB * 4]; // 13312 B [slice][b32] float4 gate partials
    __shared__ float xebuf[NB];          // 128 B
    // total 65024 B <= 65536

    const int tid = threadIdx.x;
    const int s   = tid >> 5;   // slice 0..25
    const int b32 = tid & 31;   // batch within block
    const int b   = blockIdx.x * NB + b32;

    // ---- stage weights into LDS ----
    for (int i = tid; i < RPAD * KH; i += NTHREADS) {
        int r = i / KH, k = i - r * KH;
        W1[i] = (r < HROWS && k < 51) ? Whh1[r * 51 + k] : 0.f;
    }
    for (int r = tid; r < RPAD; r += NTHREADS) {
        bs1[r] = (r < HROWS) ? (bih1[r] + bhh1[r]) : 0.f;
        wi1[r] = (r < HROWS) ? Wih1[r] : 0.f;
    }

    // per-thread layer-2 weight slice (static indexing)
    float w2r[4][2];
    #pragma unroll
    for (int g = 0; g < 4; ++g) {
        #pragma unroll
        for (int jl = 0; jl < 2; ++jl) {
            int l = 2 * s + jl;
            w2r[g][jl] = (l < 51) ? Wih2[g * 51 + l] : 0.f;
        }
    }
    float whh2r[4], bs2r[4];
    #pragma unroll
    for (int g = 0; g < 4; ++g) { whh2r[g] = Whh2[g]; bs2r[g] = bih2[g] + bhh2[g]; }

    float h1[KH];
    float c1[2];
    #pragma unroll
    for (int k = 0; k < KH; ++k) h1[k] = 0.f;
    c1[0] = 0.f; c1[1] = 0.f;
    float h2 = 0.f, c2 = 0.f;   // valid only in finisher threads (tid < 32)

    __syncthreads();

    float xr = X[b * TT];

    for (int t = 0; t < TT; ++t) {
        float xnext = X[b * TT + (t < TT - 1 ? t + 1 : TT - 1)];

        // ---- layer-1: this thread's 2 hidden units, 4 gates each ----
        #pragma unroll
        for (int jl = 0; jl < 2; ++jl) {
            const int l = 2 * s + jl;   // l==51 computes a pad unit; contained (see below)
            float acc[4];
            #pragma unroll
            for (int g = 0; g < 4; ++g) {
                int row = g * 51 + l;
                float a = bs1[row] + wi1[row] * xr;
                const float4* wr = (const float4*)&W1[row * KH];
                #pragma unroll
                for (int kq = 0; kq < 13; ++kq) {
                    float4 wv = wr[kq];
                    a += wv.x * h1[4*kq]   + wv.y * h1[4*kq+1]
                       + wv.z * h1[4*kq+2] + wv.w * h1[4*kq+3];
                }
                acc[g] = a;
            }
            float ig = fsig(acc[0]);
            float fg = fsig(acc[1]);
            float gg = ftanh_(acc[2]);
            float og = fsig(acc[3]);
            float c  = fg * c1[jl] + ig * gg;
            c1[jl] = c;
            // hbuf row 51 is written but never read back (h1[51] forced to 0);
            // l==51 c1 value is bounded (sig/tanh bounded) and its w2r is 0.
            hbuf[l * NB + b32] = og * ftanh_(c);
        }

        // ---- layer-2 gate partials over this thread's c1 slice ----
        {
            float p0 = w2r[0][0]*c1[0] + w2r[0][1]*c1[1];
            float p1 = w2r[1][0]*c1[0] + w2r[1][1]*c1[1];
            float p2 = w2r[2][0]*c1[0] + w2r[2][1]*c1[1];
            float p3 = w2r[3][0]*c1[0] + w2r[3][1]*c1[1];
            ((float4*)pbuf)[s * NB + b32] = make_float4(p0, p1, p2, p3);
        }

        __syncthreads();

        // ---- reload full h1 for next step ----
        #pragma unroll
        for (int k = 0; k < 51; ++k) h1[k] = hbuf[k * NB + b32];
        h1[51] = 0.f;

        // ---- finisher: layer-2 state update (one thread per batch elem) ----
        if (tid < NB) {
            float s0 = bs2r[0] + whh2r[0] * h2;
            float s1 = bs2r[1] + whh2r[1] * h2;
            float s2 = bs2r[2] + whh2r[2] * h2;
            float s3 = bs2r[3] + whh2r[3] * h2;
            #pragma unroll
            for (int ww = 0; ww < NSL; ++ww) {
                float4 p = ((const float4*)pbuf)[ww * NB + tid];
                s0 += p.x; s1 += p.y; s2 += p.z; s3 += p.w;
            }
            float i2 = fsig(s0), f2 = fsig(s1), g2 = ftanh_(s2), o2 = fsig(s3);
            c2 = f2 * c2 + i2 * g2;
            h2 = o2 * ftanh_(c2);
        }

        __syncthreads();
        xr = xnext;
    }

    // ---- extra step: lstm1(input=c2) then lstm2(input=new c1) -> out = new c2 ----
    if (tid < NB) xebuf[tid] = c2;
    __syncthreads();
    const float xe = xebuf[b32];

    #pragma unroll
    for (int jl = 0; jl < 2; ++jl) {
        const int l = 2 * s + jl;
        float acc[4];
        #pragma unroll
        for (int g = 0; g < 4; ++g) {
            int row = g * 51 + l;
            float a = bs1[row] + wi1[row] * xe;
            const float4* wr = (const float4*)&W1[row * KH];
            #pragma unroll
            for (int kq = 0; kq < 13; ++kq) {
                float4 wv = wr[kq];
                a += wv.x * h1[4*kq]   + wv.y * h1[4*kq+1]
                   + wv.z * h1[4*kq+2] + wv.w * h1[4*kq+3];
            }
            acc[g] = a;
        }
        float ig = fsig(acc[0]);
        float fg = fsig(acc[1]);
        float gg = ftanh_(acc[2]);
        c1[jl] = fg * c1[jl] + ig * gg;
    }
    {
        float p0 = w2r[0][0]*c1[0] + w2r[0][1]*c1[1];
        float p1 = w2r[1][0]*c1[0] + w2r[1][1]*c1[1];
        float p2 = w2r[2][0]*c1[0] + w2r[2][1]*c1[1];
        float p3 = w2r[3][0]*c1[0] + w2r[3][1]*c1[1];
        ((float4*)pbuf)[s * NB + b32] = make_float4(p0, p1, p2, p3);
    }
    __syncthreads();

    if (tid < NB) {
        float s0 = bs2r[0] + whh2r[0] * h2;
        float s1 = bs2r[1] + whh2r[1] * h2;
        float s2 = bs2r[2] + whh2r[2] * h2;
        #pragma unroll
        for (int ww = 0; ww < NSL; ++ww) {
            float4 p = ((const float4*)pbuf)[ww * NB + tid];
            s0 += p.x; s1 += p.y; s2 += p.z;
        }
        float i2 = fsig(s0), f2 = fsig(s1), g2 = ftanh_(s2);
        out[blockIdx.x * NB + tid] = f2 * c2 + i2 * g2;
    }
}

extern "C" void kernel_launch(void* const* d_in, const int* in_sizes, int n_in,
                              void* d_out, int out_size, void* d_ws, size_t ws_size,
                              hipStream_t stream) {
    const float* X    = (const float*)d_in[0];
    const float* Wih1 = (const float*)d_in[1];
    const float* Whh1 = (const float*)d_in[2];
    const float* bih1 = (const float*)d_in[3];
    const float* bhh1 = (const float*)d_in[4];
    const float* Wih2 = (const float*)d_in[5];
    const float* Whh2 = (const float*)d_in[6];
    const float* bih2 = (const float*)d_in[7];
    const float* bhh2 = (const float*)d_in[8];
    float* out = (float*)d_out;

    lstm_seq_kernel<<<256, NTHREADS, 0, stream>>>(X, Wih1, Whh1, bih1, bhh1,
                                                  Wih2, Whh2, bih2, bhh2, out);
}

// Round 3
// 3222.240 us; speedup vs baseline: 3.5647x; 1.6662x over previous
//
#include <hip/hip_runtime.h>
#include <hip/hip_fp16.h>

#define TT 512

__device__ __forceinline__ float fsig(float x){ float e=__expf(-x); return __fdividef(1.f,1.f+e); }
__device__ __forceinline__ float ftanh_(float x){ float t=__expf(-2.f*fabsf(x)); float r=__fdividef(1.f-t,1.f+t); return copysignf(r,x); }

// v_fma_mix_f32: dst.f32 = f16(src0 lo/hi) * f32(src1) + f32(src2)
#define FMA_LO(accv, wd, hh) asm("v_fma_mix_f32 %0, %1, %2, %0 op_sel:[0,0,0] op_sel_hi:[1,0,0]" : "+v"(accv) : "v"(wd), "v"(hh))
#define FMA_HI(accv, wd, hh) asm("v_fma_mix_f32 %0, %1, %2, %0 op_sel:[1,0,0] op_sel_hi:[1,0,0]" : "+v"(accv) : "v"(wd), "v"(hh))

// ---- repack Whh1 [204][51] fp32 -> f16 streams: [26 streams][13 chunks][4 b128][8 f16]
// stream s=(w*2+rh): rows R = w*16+rh*8+rl (unit-major: u=R>>2, gate g=R&3, torch row = g*51+u)
__global__ void repack_w(const float* __restrict__ Whh1, __half* __restrict__ Wp){
    int i = blockIdx.x*256 + threadIdx.x;
    if (i >= 26*416) return;
    int s = i / 416, rem = i % 416;
    int kc = rem >> 5, c32 = rem & 31;
    int j = c32 >> 3, q = c32 & 7;
    int rl = 2*j + (q>>2);
    int k  = kc*4 + ((q>>1)&1)*2 + (q&1);
    int w = s >> 1, rh = s & 1;
    int R = w*16 + rh*8 + rl;
    int u = R >> 2, g = R & 3;
    float v = (u < 51 && k < 51) ? Whh1[(g*51+u)*51 + k] : 0.f;
    Wp[i] = __float2half(v);
}

// ---- layer-1 step for this lane's 2 units (8 gate rows), plus layer-2 partial write
__device__ __forceinline__ void lstm1_step(
    const char* hin, char* hout, char* pwp,
    const float4* __restrict__ Ws,
    const float (&bs_r)[8], const float (&wi_r)[8],
    const float (&w20)[4], const float (&w21)[4],
    int sig, int rh, float xcur, float& c1a, float& c1b, bool writeH)
{
    float a0 = bs_r[0] + wi_r[0]*xcur, a1 = bs_r[1] + wi_r[1]*xcur;
    float a2 = bs_r[2] + wi_r[2]*xcur, a3 = bs_r[3] + wi_r[3]*xcur;
    float a4 = bs_r[4] + wi_r[4]*xcur, a5 = bs_r[5] + wi_r[5]*xcur;
    float a6 = bs_r[6] + wi_r[6]*xcur, a7 = bs_r[7] + wi_r[7]*xcur;

    float4 wv[3][4];
    float4 hv[3];
    #pragma unroll
    for (int j = 0; j < 4; ++j) wv[0][j] = Ws[j];
    #pragma unroll
    for (int j = 0; j < 4; ++j) wv[1][j] = Ws[4+j];
    hv[0] = *(const float4*)(hin + ((0^sig)<<4));
    hv[1] = *(const float4*)(hin + ((1^sig)<<4));

    #pragma unroll
    for (int kc = 0; kc < 13; ++kc) {
        if (kc + 2 < 13) {
            #pragma unroll
            for (int j = 0; j < 4; ++j) wv[(kc+2)%3][j] = Ws[(kc+2)*4 + j];
            hv[(kc+2)%3] = *(const float4*)(hin + (((kc+2)^sig)<<4));
        }
        const float4 hq = hv[kc%3];
        // rows 0,1
        FMA_LO(a0, wv[kc%3][0].x, hq.x); FMA_HI(a0, wv[kc%3][0].x, hq.y);
        FMA_LO(a0, wv[kc%3][0].y, hq.z); FMA_HI(a0, wv[kc%3][0].y, hq.w);
        FMA_LO(a1, wv[kc%3][0].z, hq.x); FMA_HI(a1, wv[kc%3][0].z, hq.y);
        FMA_LO(a1, wv[kc%3][0].w, hq.z); FMA_HI(a1, wv[kc%3][0].w, hq.w);
        // rows 2,3
        FMA_LO(a2, wv[kc%3][1].x, hq.x); FMA_HI(a2, wv[kc%3][1].x, hq.y);
        FMA_LO(a2, wv[kc%3][1].y, hq.z); FMA_HI(a2, wv[kc%3][1].y, hq.w);
        FMA_LO(a3, wv[kc%3][1].z, hq.x); FMA_HI(a3, wv[kc%3][1].z, hq.y);
        FMA_LO(a3, wv[kc%3][1].w, hq.z); FMA_HI(a3, wv[kc%3][1].w, hq.w);
        // rows 4,5
        FMA_LO(a4, wv[kc%3][2].x, hq.x); FMA_HI(a4, wv[kc%3][2].x, hq.y);
        FMA_LO(a4, wv[kc%3][2].y, hq.z); FMA_HI(a4, wv[kc%3][2].y, hq.w);
        FMA_LO(a5, wv[kc%3][2].z, hq.x); FMA_HI(a5, wv[kc%3][2].z, hq.y);
        FMA_LO(a5, wv[kc%3][2].w, hq.z); FMA_HI(a5, wv[kc%3][2].w, hq.w);
        // rows 6,7
        FMA_LO(a6, wv[kc%3][3].x, hq.x); FMA_HI(a6, wv[kc%3][3].x, hq.y);
        FMA_LO(a6, wv[kc%3][3].y, hq.z); FMA_HI(a6, wv[kc%3][3].y, hq.w);
        FMA_LO(a7, wv[kc%3][3].z, hq.x); FMA_HI(a7, wv[kc%3][3].z, hq.y);
        FMA_LO(a7, wv[kc%3][3].w, hq.z); FMA_HI(a7, wv[kc%3][3].w, hq.w);
    }

    float i0=fsig(a0), f0=fsig(a1), g0=ftanh_(a2), o0=fsig(a3);
    c1a = f0*c1a + i0*g0;
    float i1=fsig(a4), f1=fsig(a5), g1=ftanh_(a6), o1=fsig(a7);
    c1b = f1*c1b + i1*g1;
    if (writeH) {
        float hA = o0*ftanh_(c1a), hB = o1*ftanh_(c1b);
        *(float2*)hout = make_float2(hA, hB);
    }
    // layer-2 partials over this lane's 2 units
    float p0 = w20[0]*c1a + w21[0]*c1b;
    float p1 = w20[1]*c1a + w21[1]*c1b;
    float p2 = w20[2]*c1a + w21[2]*c1b;
    float p3 = w20[3]*c1a + w21[3]*c1b;
    p0 += __shfl_xor(p0, 32); p1 += __shfl_xor(p1, 32);
    p2 += __shfl_xor(p2, 32); p3 += __shfl_xor(p3, 32);
    float e0 = rh ? p2 : p0;
    float e1 = rh ? p3 : p1;
    *(float*)(pwp)       = e0;
    *(float*)(pwp + 128) = e1;
}

__device__ __forceinline__ void lstm2_update(const char* prp, int rh,
    const float (&bs2)[4], const float (&wh2)[4], float& h2, float& c2, bool needO)
{
    float sA = 0.f, sB = 0.f;
    #pragma unroll
    for (int wq = 0; wq < 13; ++wq) {
        sA += *(const float*)(prp + wq*512);
        sB += *(const float*)(prp + wq*512 + 128);
    }
    float oA = __shfl_xor(sA, 32), oB = __shfl_xor(sB, 32);
    float s0 = rh ? oA : sA, s1 = rh ? oB : sB;
    float s2 = rh ? sA : oA, s3 = rh ? sB : oB;
    s0 += bs2[0] + wh2[0]*h2; s1 += bs2[1] + wh2[1]*h2;
    s2 += bs2[2] + wh2[2]*h2; s3 += bs2[3] + wh2[3]*h2;
    float i2=fsig(s0), f2=fsig(s1), g2=ftanh_(s2);
    c2 = f2*c2 + i2*g2;
    if (needO) { float o2 = fsig(s3); h2 = o2*ftanh_(c2); }
}

__global__ __launch_bounds__(832, 1) void lstm_main(
    const float* __restrict__ X, const __half* __restrict__ Wp,
    const float* __restrict__ Wih1, const float* __restrict__ bih1, const float* __restrict__ bhh1,
    const float* __restrict__ Wih2, const float* __restrict__ Whh2,
    const float* __restrict__ bih2, const float* __restrict__ bhh2,
    float* __restrict__ out)
{
    // LDS: hbuf [2][32][64] f32 (16384B, XOR-swizzled 16B blocks) | pbuf [2][13][4][32] f32 (13312B) | xe[32]
    __shared__ char lds[16384 + 13312 + 128];
    float* HB = (float*)lds;
    char*  PB = lds + 16384;
    float* XE = (float*)(lds + 16384 + 13312);

    const int tid = threadIdx.x;
    const int w   = tid >> 6;
    const int rh  = (tid >> 5) & 1;
    const int b32 = tid & 31;
    const int sig = b32 & 7;
    const int b   = blockIdx.x * 32 + b32;

    for (int i = tid; i < 2048; i += 832) HB[i] = 0.f;   // zero parity-0 h state

    float bs_r[8], wi_r[8];
    #pragma unroll
    for (int j = 0; j < 8; ++j) {
        int R = w*16 + rh*8 + j;
        int u = R >> 2, g = R & 3;
        if (u < 51) { int sr = g*51 + u; bs_r[j] = bih1[sr] + bhh1[sr]; wi_r[j] = Wih1[sr]; }
        else        { bs_r[j] = 0.f; wi_r[j] = 0.f; }
    }
    float w20[4], w21[4];
    {
        int u0 = w*4 + rh*2, u1 = u0 + 1;
        #pragma unroll
        for (int g = 0; g < 4; ++g) {
            w20[g] = (u0 < 51) ? Wih2[g*51 + u0] : 0.f;
            w21[g] = (u1 < 51) ? Wih2[g*51 + u1] : 0.f;
        }
    }
    float wh2[4], bs2[4];
    #pragma unroll
    for (int g = 0; g < 4; ++g) { wh2[g] = Whh2[g]; bs2[g] = bih2[g] + bhh2[g]; }

    const float4* Ws = (const float4*)(Wp + (w*2 + rh)*416);   // 52 float4 per stream

    const char* hrd0 = (const char*)HB + b32*256;
    const char* hrd1 = hrd0 + 8192;
    char* hwr0 = (char*)HB + b32*256 + (((w ^ sig) & 15) << 4) + rh*8;
    char* hwr1 = hwr0 + 8192;
    char* pw0 = PB + w*512 + rh*256 + b32*4;
    char* pw1 = pw0 + 6656;
    const char* pr0 = PB + rh*256 + b32*4;
    const char* pr1 = pr0 + 6656;

    float c1a = 0.f, c1b = 0.f, h2 = 0.f, c2 = 0.f;

    __syncthreads();

    float xr = X[b*TT];

    for (int t = 0; t < TT; t += 2) {
        float xa = X[b*TT + t + 1];
        lstm1_step(hrd0, hwr1, pw1, Ws, bs_r, wi_r, w20, w21, sig, rh, xr, c1a, c1b, true);
        __syncthreads();
        if (w == 0) lstm2_update(pr1, rh, bs2, wh2, h2, c2, true);
        float xbn = (t + 2 < TT) ? X[b*TT + t + 2] : 0.f;
        lstm1_step(hrd1, hwr0, pw0, Ws, bs_r, wi_r, w20, w21, sig, rh, xa, c1a, c1b, true);
        __syncthreads();
        if (w == 0) lstm2_update(pr0, rh, bs2, wh2, h2, c2, true);
        xr = xbn;
    }

    // extra step: lstm1(input=c2) -> c1_new; lstm2(input=c1_new) -> out = new c2
    if (w == 0 && rh == 0) XE[b32] = c2;
    __syncthreads();
    float xre = XE[b32];
    lstm1_step(hrd0, hwr1, pw1, Ws, bs_r, wi_r, w20, w21, sig, rh, xre, c1a, c1b, false);
    __syncthreads();
    if (w == 0) {
        lstm2_update(pr1, rh, bs2, wh2, h2, c2, false);
        if (rh == 0) out[b] = c2;
    }
}

extern "C" void kernel_launch(void* const* d_in, const int* in_sizes, int n_in,
                              void* d_out, int out_size, void* d_ws, size_t ws_size,
                              hipStream_t stream) {
    const float* X    = (const float*)d_in[0];
    const float* Wih1 = (const float*)d_in[1];
    const float* Whh1 = (const float*)d_in[2];
    const float* bih1 = (const float*)d_in[3];
    const float* bhh1 = (const float*)d_in[4];
    const float* Wih2 = (const float*)d_in[5];
    const float* Whh2 = (const float*)d_in[6];
    const float* bih2 = (const float*)d_in[7];
    const float* bhh2 = (const float*)d_in[8];
    float* out = (float*)d_out;
    __half* Wp = (__half*)d_ws;   // 26*416 halfs = 21632 B

    repack_w<<<(26*416 + 255)/256, 256, 0, stream>>>(Whh1, Wp);
    lstm_main<<<256, 832, 0, stream>>>(X, Wp, Wih1, bih1, bhh1, Wih2, Whh2, bih2, bhh2, out);
}

// Round 4
// 1087.880 us; speedup vs baseline: 10.5585x; 2.9619x over previous
//
#include <hip/hip_runtime.h>
#include <hip/hip_fp16.h>

#define TT 512

typedef _Float16 f16;
typedef _Float16 f16x8 __attribute__((ext_vector_type(8)));
typedef float f32x4 __attribute__((ext_vector_type(4)));

__device__ __forceinline__ float fsig(float x){ float e=__expf(-x); return __fdividef(1.f,1.f+e); }
__device__ __forceinline__ float ftanh_(float x){ float t=__expf(-2.f*fabsf(x)); float r=__fdividef(1.f-t,1.f+t); return copysignf(r,x); }

// Repack:
//  Wp  (f16): [13 m][2 kt][64 lane][8 b]  A-fragments for mfma_f32_16x16x32_f16.
//             A[i][k]: i = lane&15 -> packed row r = m*16 + (lane&15)  (r = 4*u + gate, unit-major)
//                      k = kt*32 + (lane>>4)*8 + b                      (k = source hidden unit)
//  Wp2 (f32): [56 u][4 g] = Wih2[g*51+u] (zero-padded)
__global__ void repack_w(const float* __restrict__ Whh1, const float* __restrict__ Wih2,
                         f16* __restrict__ Wp, float* __restrict__ Wp2)
{
    int i = blockIdx.x*256 + threadIdx.x;
    if (i < 13*2*64*8) {
        int b    = i & 7;
        int lane = (i >> 3) & 63;
        int kt   = (i >> 9) & 1;
        int m    = i >> 10;
        int r = m*16 + (lane & 15);
        int u = r >> 2, g = r & 3;
        int k = kt*32 + (lane >> 4)*8 + b;
        float v = (u < 51 && k < 51) ? Whh1[(g*51+u)*51 + k] : 0.f;
        Wp[i] = (f16)v;
    }
    if (i < 224) {
        int u = i >> 2, g = i & 3;
        Wp2[i] = (u < 51) ? Wih2[g*51 + u] : 0.f;
    }
}

__global__ __launch_bounds__(832, 1) void lstm_main(
    const float* __restrict__ X, const f16* __restrict__ Wp, const float* __restrict__ Wp2,
    const float* __restrict__ Wih1, const float* __restrict__ bih1, const float* __restrict__ bhh1,
    const float* __restrict__ Whh2, const float* __restrict__ bih2, const float* __restrict__ bhh2,
    float* __restrict__ out)
{
    // HB: h in B-fragment layout: [parity][o = u>>3][batch 0..31][e = u&7] f16  (2*8*32*8*2B = 8 KB)
    // CB: c1 f32 for layer-2:     [parity][batch][unit 0..55]               (2*32*56*4B = 14 KB)
    __shared__ __align__(16) f16  HB[2][8][32][8];
    __shared__ __align__(16) float CB[2][32][56];
    __shared__ float XE[32];

    const int tid  = threadIdx.x;
    const int w    = tid >> 6;      // wave = M-tile, 0..12
    const int lane = tid & 63;
    const int q    = lane >> 4;     // lane quarter
    const int jl   = lane & 15;     // batch-in-tile (A row / B col / C col index)
    const int bb   = blockIdx.x * 32;

    for (int i = tid; i < 2*8*32*8; i += 832) ((f16*)HB)[i] = (f16)0.f;
    for (int i = tid; i < 2*32*56;  i += 832) ((float*)CB)[i] = 0.f;

    // resident A fragments (weights) — loaded once, 8 VGPRs
    f16x8 A0 = *(const f16x8*)(Wp + (w*2+0)*512 + lane*8);
    f16x8 A1 = *(const f16x8*)(Wp + (w*2+1)*512 + lane*8);

    // C rows for this lane = gates 0..3 of unit u_c
    const int u_c = w*4 + q;
    float bs[4], wi[4];
    #pragma unroll
    for (int g = 0; g < 4; ++g) {
        if (u_c < 51) { int rt = g*51 + u_c; bs[g] = bih1[rt] + bhh1[rt]; wi[g] = Wih1[rt]; }
        else          { bs[g] = 0.f; wi[g] = 0.f; }
    }
    float wh2[4], bs2[4];
    #pragma unroll
    for (int g = 0; g < 4; ++g) { wh2[g] = Whh2[g]; bs2[g] = bih2[g] + bhh2[g]; }

    float c1a = 0.f, c1b = 0.f;           // cell state, lane-local (batch jl, jl+16)
    float c2 = 0.f, h2 = 0.f;             // finisher wave only
    const int fj = lane & 31, fhalf = lane >> 5;

    __syncthreads();

    const float* xp0 = X + (size_t)(bb + jl)      * TT;
    const float* xp1 = X + (size_t)(bb + 16 + jl) * TT;
    float xc0 = xp0[0], xc1 = xp1[0];
    int rp = 0;

    for (int t = 0; t < TT; ++t) {
        int tn = (t+1 < TT) ? t+1 : t;
        float xn0 = xp0[tn], xn1 = xp1[tn];

        // B fragments (h) from HB[rp] — one b128 each, distinct 16B blocks
        f16x8 B00 = *(const f16x8*)&HB[rp][q    ][jl    ][0];
        f16x8 B10 = *(const f16x8*)&HB[rp][4 + q][jl    ][0];
        f16x8 B01 = *(const f16x8*)&HB[rp][q    ][16+jl][0];
        f16x8 B11 = *(const f16x8*)&HB[rp][4 + q][16+jl][0];

        f32x4 acc0, acc1;
        #pragma unroll
        for (int g = 0; g < 4; ++g) { acc0[g] = bs[g] + wi[g]*xc0; acc1[g] = bs[g] + wi[g]*xc1; }
        acc0 = __builtin_amdgcn_mfma_f32_16x16x32_f16(A0, B00, acc0, 0,0,0);
        acc0 = __builtin_amdgcn_mfma_f32_16x16x32_f16(A1, B10, acc0, 0,0,0);
        acc1 = __builtin_amdgcn_mfma_f32_16x16x32_f16(A0, B01, acc1, 0,0,0);
        acc1 = __builtin_amdgcn_mfma_f32_16x16x32_f16(A1, B11, acc1, 0,0,0);

        // epilogue: cell update lane-local; h -> f16 B-layout; c1 -> CB for layer 2
        {
            float i1=fsig(acc0[0]), f1=fsig(acc0[1]), g1=ftanh_(acc0[2]), o1=fsig(acc0[3]);
            c1a = f1*c1a + i1*g1;
            HB[rp^1][u_c>>3][jl][u_c&7] = (f16)(o1*ftanh_(c1a));
            CB[rp^1][jl][u_c] = c1a;
        }
        {
            float i1=fsig(acc1[0]), f1=fsig(acc1[1]), g1=ftanh_(acc1[2]), o1=fsig(acc1[3]);
            c1b = f1*c1b + i1*g1;
            HB[rp^1][u_c>>3][16+jl][u_c&7] = (f16)(o1*ftanh_(c1b));
            CB[rp^1][16+jl][u_c] = c1b;
        }

        __syncthreads();

        // finisher: layer-2 LSTM (wave 12; 2 lanes per batch: units 0..27 / 28..55)
        if (w == 12) {
            float s0=0.f, s1=0.f, s2=0.f, s3=0.f;
            #pragma unroll
            for (int o = 0; o < 7; ++o) {
                f32x4 cv = *(const f32x4*)&CB[rp^1][fj][fhalf*28 + o*4];
                #pragma unroll
                for (int uu = 0; uu < 4; ++uu) {
                    f32x4 wv = *(const f32x4*)(Wp2 + (fhalf*28 + o*4 + uu)*4);
                    s0 += wv[0]*cv[uu]; s1 += wv[1]*cv[uu];
                    s2 += wv[2]*cv[uu]; s3 += wv[3]*cv[uu];
                }
            }
            s0 += __shfl_xor(s0, 32); s1 += __shfl_xor(s1, 32);
            s2 += __shfl_xor(s2, 32); s3 += __shfl_xor(s3, 32);
            s0 += bs2[0] + wh2[0]*h2;  s1 += bs2[1] + wh2[1]*h2;
            s2 += bs2[2] + wh2[2]*h2;  s3 += bs2[3] + wh2[3]*h2;
            float i2=fsig(s0), f2=fsig(s1), g2=ftanh_(s2), o2=fsig(s3);
            c2 = f2*c2 + i2*g2;
            h2 = o2*ftanh_(c2);
        }

        rp ^= 1;
        xc0 = xn0; xc1 = xn1;
    }

    // ---- extra step: lstm1(input=c2) -> c1'; lstm2(input=c1') -> out = c2' ----
    if (w == 12 && lane < 32) XE[lane] = c2;
    __syncthreads();
    {
        float xe0 = XE[jl], xe1 = XE[16+jl];
        f16x8 B00 = *(const f16x8*)&HB[rp][q    ][jl    ][0];
        f16x8 B10 = *(const f16x8*)&HB[rp][4 + q][jl    ][0];
        f16x8 B01 = *(const f16x8*)&HB[rp][q    ][16+jl][0];
        f16x8 B11 = *(const f16x8*)&HB[rp][4 + q][16+jl][0];
        f32x4 acc0, acc1;
        #pragma unroll
        for (int g = 0; g < 4; ++g) { acc0[g] = bs[g] + wi[g]*xe0; acc1[g] = bs[g] + wi[g]*xe1; }
        acc0 = __builtin_amdgcn_mfma_f32_16x16x32_f16(A0, B00, acc0, 0,0,0);
        acc0 = __builtin_amdgcn_mfma_f32_16x16x32_f16(A1, B10, acc0, 0,0,0);
        acc1 = __builtin_amdgcn_mfma_f32_16x16x32_f16(A0, B01, acc1, 0,0,0);
        acc1 = __builtin_amdgcn_mfma_f32_16x16x32_f16(A1, B11, acc1, 0,0,0);
        {
            float i1=fsig(acc0[0]), f1=fsig(acc0[1]), g1=ftanh_(acc0[2]);
            c1a = f1*c1a + i1*g1;
            CB[rp^1][jl][u_c] = c1a;
        }
        {
            float i1=fsig(acc1[0]), f1=fsig(acc1[1]), g1=ftanh_(acc1[2]);
            c1b = f1*c1b + i1*g1;
            CB[rp^1][16+jl][u_c] = c1b;
        }
    }
    __syncthreads();
    if (w == 12) {
        float s0=0.f, s1=0.f, s2=0.f;
        #pragma unroll
        for (int o = 0; o < 7; ++o) {
            f32x4 cv = *(const f32x4*)&CB[rp^1][fj][fhalf*28 + o*4];
            #pragma unroll
            for (int uu = 0; uu < 4; ++uu) {
                f32x4 wv = *(const f32x4*)(Wp2 + (fhalf*28 + o*4 + uu)*4);
                s0 += wv[0]*cv[uu]; s1 += wv[1]*cv[uu]; s2 += wv[2]*cv[uu];
            }
        }
        s0 += __shfl_xor(s0, 32); s1 += __shfl_xor(s1, 32); s2 += __shfl_xor(s2, 32);
        s0 += bs2[0] + wh2[0]*h2;
        s1 += bs2[1] + wh2[1]*h2;
        s2 += bs2[2] + wh2[2]*h2;
        float i2=fsig(s0), f2=fsig(s1), g2=ftanh_(s2);
        float c2n = f2*c2 + i2*g2;
        if (lane < 32) out[bb + fj] = c2n;
    }
}

extern "C" void kernel_launch(void* const* d_in, const int* in_sizes, int n_in,
                              void* d_out, int out_size, void* d_ws, size_t ws_size,
                              hipStream_t stream) {
    const float* X    = (const float*)d_in[0];
    const float* Wih1 = (const float*)d_in[1];
    const float* Whh1 = (const float*)d_in[2];
    const float* bih1 = (const float*)d_in[3];
    const float* bhh1 = (const float*)d_in[4];
    const float* Wih2 = (const float*)d_in[5];
    const float* Whh2 = (const float*)d_in[6];
    const float* bih2 = (const float*)d_in[7];
    const float* bhh2 = (const float*)d_in[8];
    float* out = (float*)d_out;

    f16*   Wp  = (f16*)d_ws;                        // 13312 f16 = 26624 B
    float* Wp2 = (float*)((char*)d_ws + 26624);     // 224 f32

    repack_w<<<52, 256, 0, stream>>>(Whh1, Wih2, Wp, Wp2);
    lstm_main<<<256, 832, 0, stream>>>(X, Wp, Wp2, Wih1, bih1, bhh1, Whh2, bih2, bhh2, out);
}

// Round 6
// 663.112 us; speedup vs baseline: 17.3219x; 1.6406x over previous
//
#include <hip/hip_runtime.h>

#define TT 512

typedef _Float16 f16;
typedef _Float16 f16x8 __attribute__((ext_vector_type(8)));
typedef float f32x4 __attribute__((ext_vector_type(4)));

__device__ __forceinline__ float fsig(float x){
    return __builtin_amdgcn_rcpf(1.f + __expf(-x));
}
__device__ __forceinline__ float ftanh_(float x){
    return 2.f * __builtin_amdgcn_rcpf(1.f + __expf(-2.f*x)) - 1.f;
}

// Wp (f16): [13 m][2 kt][64 lane][8 b] A-fragments for mfma_f32_16x16x32_f16
//   row r = m*16 + (lane&15), unit-major r = 4*u+g; k = kt*32 + (lane>>4)*8 + b
// Wp2 (f32): [52 u][4 g] = Wih2[g*51+u], zero-padded
__global__ void repack_w(const float* __restrict__ Whh1, const float* __restrict__ Wih2,
                         f16* __restrict__ Wp, float* __restrict__ Wp2)
{
    int i = blockIdx.x*256 + threadIdx.x;
    if (i < 13*2*64*8) {
        int b    = i & 7;
        int lane = (i >> 3) & 63;
        int kt   = (i >> 9) & 1;
        int m    = i >> 10;
        int r = m*16 + (lane & 15);
        int u = r >> 2, g = r & 3;
        int k = kt*32 + (lane >> 4)*8 + b;
        float v = (u < 51 && k < 51) ? Whh1[(g*51+u)*51 + k] : 0.f;
        Wp[i] = (f16)v;
    }
    if (i < 208) {
        int u = i >> 2, g = i & 3;
        Wp2[i] = (u < 51) ? Wih2[g*51 + u] : 0.f;
    }
}

__global__ __launch_bounds__(896, 7) void lstm_main(
    const float* __restrict__ X, const f16* __restrict__ Wp, const float* __restrict__ Wp2,
    const float* __restrict__ Wih1, const float* __restrict__ bih1, const float* __restrict__ bhh1,
    const float* __restrict__ Whh2, const float* __restrict__ bih2, const float* __restrict__ bhh2,
    float* __restrict__ out)
{
    // HB: h in B-fragment layout [parity][o=u>>3][batch][e=u&7] f16   (4096 B)
    // PB: layer-2 partials [parity][28 chunks][16 batch][4 gates] f32 (14336 B; chunks 26,27 stay 0)
    __shared__ __align__(16) f16   HB[2][8][16][8];
    __shared__ __align__(16) float PB[2][28][16][4];
    __shared__ float XE[16];

    const int tid  = threadIdx.x;
    const int w    = tid >> 6;        // 0..12 = lstm1 M-tiles, 13 = layer-2 wave
    const int lane = tid & 63;
    const int q    = lane >> 4;
    const int jl   = lane & 15;       // batch within block
    const int bb   = blockIdx.x * 16;

    // zero HB (pad rows must be 0) and ALL of PB (both parities: pad chunks 26,27
    // are read by wave 13 every step and never written — R5 bug was zeroing only half)
    for (int i = tid; i < 1024; i += 896) ((unsigned*)HB)[i] = 0u;
    for (int i = tid; i < 2*28*16*4; i += 896) ((unsigned*)PB)[i] = 0u;

    const int wm  = (w < 13) ? w : 0;          // safe index for wave 13's dummy loads
    const int u_c = wm*4 + q;                  // this lane's unit (lstm1 waves)

    f16x8 A0 = *(const f16x8*)(Wp + (wm*2+0)*512 + lane*8);
    f16x8 A1 = *(const f16x8*)(Wp + (wm*2+1)*512 + lane*8);
    f32x4 w2q = *(const f32x4*)(Wp2 + u_c*4);

    float bs[4], wi[4];
    #pragma unroll
    for (int g = 0; g < 4; ++g) {
        if (u_c < 51) { int rt = g*51 + u_c; bs[g] = bih1[rt] + bhh1[rt]; wi[g] = Wih1[rt]; }
        else          { bs[g] = 0.f; wi[g] = 0.f; }
    }
    float wh2[4], bs2[4];
    #pragma unroll
    for (int g = 0; g < 4; ++g) { wh2[g] = Whh2[g]; bs2[g] = bih2[g] + bhh2[g]; }

    float c1 = 0.f;               // lstm1 lanes: cell state of (u_c, batch jl)
    float c2 = 0.f, h2 = 0.f;     // wave 13: layer-2 state (redundant per 4 lanes/batch)
    const int s13 = lane >> 4, b13 = lane & 15;

    __syncthreads();

    const float* xp = X + (size_t)(bb + jl) * TT;
    float xc = xp[0];

    #pragma unroll 2
    for (int t = 0; t < TT; ++t) {
        const int rp = t & 1;
        if (w < 13) {
            float xn = xp[(t+1 < TT) ? t+1 : t];

            f16x8 B0 = *(const f16x8*)&HB[rp][q    ][jl][0];
            f16x8 B1 = *(const f16x8*)&HB[rp][4 + q][jl][0];
            f32x4 acc;
            #pragma unroll
            for (int g = 0; g < 4; ++g) acc[g] = bs[g] + wi[g]*xc;
            acc = __builtin_amdgcn_mfma_f32_16x16x32_f16(A0, B0, acc, 0,0,0);
            acc = __builtin_amdgcn_mfma_f32_16x16x32_f16(A1, B1, acc, 0,0,0);

            float ig = fsig(acc[0]), fg = fsig(acc[1]), gg = ftanh_(acc[2]), og = fsig(acc[3]);
            c1 = fg*c1 + ig*gg;
            HB[rp^1][u_c>>3][jl][u_c&7] = (f16)(og * ftanh_(c1));

            // layer-2 partials: quarter-pair pre-reduce (xor16), halves stored as chunks
            f32x4 p;
            #pragma unroll
            for (int g = 0; g < 4; ++g) p[g] = w2q[g] * c1;
            #pragma unroll
            for (int g = 0; g < 4; ++g) p[g] += __shfl_xor(p[g], 16);
            if (!(lane & 16))
                *(f32x4*)&PB[rp^1][w*2 + (lane>>5)][jl][0] = p;

            xc = xn;
        } else if (t > 0) {
            // layer-2 LSTM for step t-1 (partials sealed in PB[rp] by previous barrier)
            f32x4 S; S[0]=S[1]=S[2]=S[3]=0.f;
            #pragma unroll
            for (int k = 0; k < 7; ++k) {
                f32x4 v = *(const f32x4*)&PB[rp][s13 + 4*k][b13][0];
                S += v;
            }
            #pragma unroll
            for (int g = 0; g < 4; ++g) { S[g] += __shfl_xor(S[g], 16); S[g] += __shfl_xor(S[g], 32); }
            float g0 = S[0] + bs2[0] + wh2[0]*h2;
            float g1 = S[1] + bs2[1] + wh2[1]*h2;
            float g2 = S[2] + bs2[2] + wh2[2]*h2;
            float g3 = S[3] + bs2[3] + wh2[3]*h2;
            float i2 = fsig(g0), f2 = fsig(g1), gg2 = ftanh_(g2), o2 = fsig(g3);
            c2 = f2*c2 + i2*gg2;
            h2 = o2*ftanh_(c2);
        }
        __syncthreads();
    }
    // parity after loop: step 511 wrote HB[0], PB[0]

    // wave 13: layer-2 for step 511, then publish c2
    if (w == 13) {
        f32x4 S; S[0]=S[1]=S[2]=S[3]=0.f;
        #pragma unroll
        for (int k = 0; k < 7; ++k) {
            f32x4 v = *(const f32x4*)&PB[0][s13 + 4*k][b13][0];
            S += v;
        }
        #pragma unroll
        for (int g = 0; g < 4; ++g) { S[g] += __shfl_xor(S[g], 16); S[g] += __shfl_xor(S[g], 32); }
        float g0 = S[0] + bs2[0] + wh2[0]*h2;
        float g1 = S[1] + bs2[1] + wh2[1]*h2;
        float g2 = S[2] + bs2[2] + wh2[2]*h2;
        float g3 = S[3] + bs2[3] + wh2[3]*h2;
        float i2 = fsig(g0), f2 = fsig(g1), gg2 = ftanh_(g2), o2 = fsig(g3);
        c2 = f2*c2 + i2*gg2;
        h2 = o2*ftanh_(c2);
        if (lane < 16) XE[lane] = c2;
    }
    __syncthreads();

    // extra step: lstm1(input = c2) -> c1'
    if (w < 13) {
        float xe = XE[jl];
        f16x8 B0 = *(const f16x8*)&HB[0][q    ][jl][0];
        f16x8 B1 = *(const f16x8*)&HB[0][4 + q][jl][0];
        f32x4 acc;
        #pragma unroll
        for (int g = 0; g < 4; ++g) acc[g] = bs[g] + wi[g]*xe;
        acc = __builtin_amdgcn_mfma_f32_16x16x32_f16(A0, B0, acc, 0,0,0);
        acc = __builtin_amdgcn_mfma_f32_16x16x32_f16(A1, B1, acc, 0,0,0);
        float ig = fsig(acc[0]), fg = fsig(acc[1]), gg = ftanh_(acc[2]);
        c1 = fg*c1 + ig*gg;
        f32x4 p;
        #pragma unroll
        for (int g = 0; g < 4; ++g) p[g] = w2q[g] * c1;
        #pragma unroll
        for (int g = 0; g < 4; ++g) p[g] += __shfl_xor(p[g], 16);
        if (!(lane & 16))
            *(f32x4*)&PB[1][w*2 + (lane>>5)][jl][0] = p;
    }
    __syncthreads();

    // final: lstm2 gates on c1' -> out = new c2
    if (w == 13) {
        f32x4 S; S[0]=S[1]=S[2]=S[3]=0.f;
        #pragma unroll
        for (int k = 0; k < 7; ++k) {
            f32x4 v = *(const f32x4*)&PB[1][s13 + 4*k][b13][0];
            S += v;
        }
        #pragma unroll
        for (int g = 0; g < 3; ++g) { S[g] += __shfl_xor(S[g], 16); S[g] += __shfl_xor(S[g], 32); }
        float g0 = S[0] + bs2[0] + wh2[0]*h2;
        float g1 = S[1] + bs2[1] + wh2[1]*h2;
        float g2 = S[2] + bs2[2] + wh2[2]*h2;
        float i2 = fsig(g0), f2 = fsig(g1), gg2 = ftanh_(g2);
        float c2n = f2*c2 + i2*gg2;
        if (lane < 16) out[bb + lane] = c2n;
    }
}

extern "C" void kernel_launch(void* const* d_in, const int* in_sizes, int n_in,
                              void* d_out, int out_size, void* d_ws, size_t ws_size,
                              hipStream_t stream) {
    const float* X    = (const float*)d_in[0];
    const float* Wih1 = (const float*)d_in[1];
    const float* Whh1 = (const float*)d_in[2];
    const float* bih1 = (const float*)d_in[3];
    const float* bhh1 = (const float*)d_in[4];
    const float* Wih2 = (const float*)d_in[5];
    const float* Whh2 = (const float*)d_in[6];
    const float* bih2 = (const float*)d_in[7];
    const float* bhh2 = (const float*)d_in[8];
    float* out = (float*)d_out;

    f16*   Wp  = (f16*)d_ws;                      // 13312 f16 = 26624 B
    float* Wp2 = (float*)((char*)d_ws + 26624);   // 208 f32

    repack_w<<<52, 256, 0, stream>>>(Whh1, Wih2, Wp, Wp2);
    lstm_main<<<512, 896, 0, stream>>>(X, Wp, Wp2, Wih1, bih1, bhh1, Whh2, bih2, bhh2, out);
}